// Round 14
// baseline (223.713 us; speedup 1.0000x reference)
//
#include <hip/hip_runtime.h>
#include <stdint.h>
#include <string.h>

#define L_SEQ 2048
#define B_SZ 2
#define NHH 8
#define HDD 128
#define C_SZ 1024
#define EMB_D 33
#define ORD 64
#define BANDS 16
#define FSTRIDE (L_SEQ + 256)   // 256 leading zeros per filter row for causal masking
#define FRSG_S 2176             // FRSg row length (f16); z in [0,2168) is read

typedef _Float16 f16;
typedef f16 f16x8 __attribute__((ext_vector_type(8)));
typedef f16 f16x4 __attribute__((ext_vector_type(4)));
typedef float f32x4 __attribute__((ext_vector_type(4)));

// ---------------------------------------------------------------------------
// Kernel 1: hyena filter MLP -> filt[hd][FSTRIDE] f32 (row = 256 zeros | 2048 taps)
// filt[hd][lag 0] += D[hd]  (absorbs the kv*D term).   (verified R3-R13)
// ---------------------------------------------------------------------------
__global__ void filter_kernel(const float* __restrict__ w0, const float* __restrict__ b0,
                              const float* __restrict__ w1, const float* __restrict__ b1,
                              const float* __restrict__ w2, const float* __restrict__ b2,
                              const float* __restrict__ fr, const float* __restrict__ wf,
                              const float* __restrict__ md, const float* __restrict__ Dv,
                              float* __restrict__ filt) {
  int tid = threadIdx.x;
  int o = tid & 63;
  int lq = tid >> 6;                 // 0..3
  int l = blockIdx.x * 4 + lq;

  if (blockIdx.x < 128) filt[(size_t)blockIdx.x * FSTRIDE + tid] = 0.0f;

  __shared__ float zs[4][EMB_D];
  __shared__ float hs[4][ORD];
  __shared__ float gs[4][ORD];

  float t = (float)l / (float)(L_SEQ - 1);
  float wang = 6.2831853071795864f * (float)l / (float)L_SEQ;
  const float fstep = (15.0f - 1e-4f) / 15.0f;

  if (o == 0) zs[lq][0] = t;
  if (o >= 1 && o < 1 + BANDS) {
    int j = o - 1;
    float fj = 1e-4f + fstep * (float)j;
    zs[lq][1 + j] = cosf(wang * fj);
  }
  if (o >= 1 + BANDS && o < 1 + 2 * BANDS) {
    int j = o - 1 - BANDS;
    float fj = 1e-4f + fstep * (float)j;
    zs[lq][1 + BANDS + j] = -sinf(wang * fj);
  }
  __syncthreads();

  float fo = fr[o];
  float a = b0[o];
  for (int e = 0; e < EMB_D; ++e) a += zs[lq][e] * w0[o * EMB_D + e];
  hs[lq][o] = sinf(fo * a);
  __syncthreads();

  a = b1[o];
  for (int e = 0; e < ORD; ++e) a += hs[lq][e] * w1[o * ORD + e];
  gs[lq][o] = sinf(fo * a);
  __syncthreads();

  a = b2[o];
  for (int e = 0; e < ORD; ++e) a += gs[lq][e] * w2[o * ORD + e];
  float h3 = sinf(fo * a);
  __syncthreads();
  hs[lq][o] = h3;
  __syncthreads();

  #pragma unroll
  for (int pass = 0; pass < 2; ++pass) {
    int hd = pass * 64 + o;
    float acc = 0.0f;
    for (int e = 0; e < ORD; ++e) acc += hs[lq][e] * wf[hd * ORD + e];
    float val = acc * expf(-t * fabsf(md[hd]));
    if (l == 0) val += Dv[hd];   // absorb D term into lag-0 tap
    filt[(size_t)hd * FSTRIDE + 256 + l] = val;
  }
}

// ---------------------------------------------------------------------------
// Kernel 1b: FRSg prep — FRSg[hd][a][z] = (f16) W_hd[2047 - z - a]
// (reversed filter, 8 shift copies, in GLOBAL memory; af reads go through
// L1/L2 instead of the LDS pipe). frow[-256..2047] valid (zero pad).
// ---------------------------------------------------------------------------
__global__ void frs_prep(const float* __restrict__ filt, f16* __restrict__ FRSg) {
  int hd = blockIdx.x;               // 128
  int tid = threadIdx.x;             // 256
  const float* frow = filt + (size_t)hd * FSTRIDE + 256;
  for (int a = 0; a < 8; ++a)
    for (int z = tid; z < FRSG_S; z += 256)
      FRSg[((size_t)hd * 8 + a) * FRSG_S + z] = (f16)frow[2047 - z - a];
}

// ---------------------------------------------------------------------------
// Kernel 2: depthwise causal 3-tap conv + layout transform.
// q -> AqT16[b][hd][n1][l]  f16 (transposed; epilogue reads f16x4 runs of l)
// k -> Akt16, v -> Avt16: chunk-blocked swizzled f16 tiles
//   [b][hd][chunk=l>>7][2048B]; elem (n, m=l&127) at byte n*256 + (2m ^ (n<<4))
// ---------------------------------------------------------------------------
#define TLC 64
__global__ void shortconv_kernel(const float* __restrict__ q_in,
                                 const float* __restrict__ k_in,
                                 const float* __restrict__ v_in,
                                 const float* __restrict__ scw,
                                 const float* __restrict__ scb,
                                 f16* __restrict__ AqT16, f16* __restrict__ Akt16,
                                 f16* __restrict__ Avt16) {
  int bid = blockIdx.x;
  int lt = bid & 31;
  int np = (bid >> 5) & 7;
  int b = bid >> 8;
  int l0 = lt * TLC;
  int tid = threadIdx.x;

  __shared__ float xs[TLC + 2][HDD + 4];
  __shared__ float wcs[HDD][4];

  const float* ins[3] = {q_in, k_in, v_in};

  for (int tsr = 0; tsr < 3; ++tsr) {
    const float* x = ins[tsr];
    if (tid < HDD) {
      int c = np * HDD + tid;
      wcs[tid][0] = scw[(tsr * C_SZ + c) * 3 + 0];
      wcs[tid][1] = scw[(tsr * C_SZ + c) * 3 + 1];
      wcs[tid][2] = scw[(tsr * C_SZ + c) * 3 + 2];
      wcs[tid][3] = scb[tsr * C_SZ + c];
    }
    for (int idx = tid; idx < (TLC + 2) * HDD; idx += 256) {
      int row = idx >> 7, hn = idx & 127;
      int l = l0 - 2 + row;
      float val = 0.0f;
      if (l >= 0) val = x[(((size_t)l * B_SZ + b) * NHH + np) * HDD + hn];
      xs[row][hn] = val;
    }
    __syncthreads();

    int n1 = tid & 7;
    int lp = tid >> 3;
    for (int hdi = 0; hdi < 16; ++hdi) {
      int hn = hdi * 8 + n1;
      float cw0 = wcs[hn][0], cw1 = wcs[hn][1], cw2 = wcs[hn][2], cb = wcs[hn][3];
      int hd = np * 16 + hdi;
      #pragma unroll
      for (int half = 0; half < 2; ++half) {
        int ll = half * 32 + lp;
        float y = cb + cw0 * xs[ll][hn] + cw1 * xs[ll + 1][hn]
                     + cw2 * xs[ll + 2][hn];
        int l = l0 + ll;
        if (tsr == 0) {
          AqT16[(((size_t)b * HDD + hd) * NHH + n1) * L_SEQ + l] = (f16)y;
        } else {
          int ch = l >> 7, m = l & 127;
          int off = (n1 << 8) | ((m << 1) ^ (n1 << 4));   // swizzled byte in tile
          char* base = (tsr == 1) ? (char*)Akt16 : (char*)Avt16;
          *(f16*)(base + ((((size_t)(b * HDD + hd)) * 16 + ch) << 11) + off) = (f16)y;
        }
      }
    }
    __syncthreads();
  }
}

// ---------------------------------------------------------------------------
// Kernel 3 (MFMA v9): barrier-free tile-per-wave.
//   G[l,n] = sum_{m<=l} W[l-m] * U[m,n],  U[m,n1*8+n2] = Av[m,n1]*Ak[m,n2]
//   out[l,n2] = sum_n1 Aq[l,n1] * G[l,n1*8+n2]
// Grid 512 = (g, b, hd); wave w independently owns tiles tA=g*4+w then
// tB=15-tA (17 chunk-units each, balanced). Per unit (128 MFMA): 14 Toeplitz
// A-frags loaded from GLOBAL FRSg (L1/L2; off the LDS pipe), U tile staged
// into WAVE-PRIVATE LDS dbuf via global_load_lds (no barriers anywhere);
// vmcnt(4) = only wait (4 = in-flight next-chunk DMA). 20 clean LDS reads
// per 128 MFMA.  XCD swizzle: slot=(g*256+b*128+hd) -> same (b,hd) shares L2.
// mfma_f32_16x16x32_f16: A row=lane&15, k=(lane>>4)*8+e; B col=lane&15,
// k=(lane>>4)*8+e; C/D col=lane&15, row=(lane>>4)*4+reg.  (verified R6-R13)
// ---------------------------------------------------------------------------
__global__ void __launch_bounds__(256, 2)
hyena_main(const f16* __restrict__ AqT16, const f16* __restrict__ Akt16,
           const f16* __restrict__ Avt16, const f16* __restrict__ FRSg,
           float* __restrict__ out) {
  int bid = blockIdx.x;            // 512: slot = g*256 + (b*128+hd)
  int g  = bid >> 8;
  int hd = bid & 127;
  int b  = (bid >> 7) & 1;
  int tid = threadIdx.x;
  int w = tid >> 6;                // wave 0..3
  int lane = tid & 63;
  int r = lane & 15;               // A row / B col within 16
  int p = lane >> 4;               // k part 0..3
  int a = (15 - r) & 7;            // FRSg shift-copy class

  __shared__ f16 AVp[4][2][1024];  // wave-private swizzled U tiles (16 KB)
  __shared__ f16 AKp[4][2][1024];  //                               (16 KB)

  const char* avtg = (const char*)Avt16 + (((size_t)(b * HDD + hd)) * 16 << 11);
  const char* aktg = (const char*)Akt16 + (((size_t)(b * HDD + hd)) * 16 << 11);
  const f16* aqtb = AqT16 + ((size_t)b * HDD + hd) * NHH * L_SEQ;
  // per-lane af base: f[dd] = *(f16x8*)(aflane + dy + 16*dd)
  const f16* aflane = FRSg + (size_t)hd * 8 * FRSG_S + a * FRSG_S
                      - (r + a) + 8 * p - 112;
  int np = hd >> 4, hnb = (hd & 15) * 8;

  f32x4 acc[8][4];
  #pragma unroll
  for (int mt = 0; mt < 8; ++mt)
    #pragma unroll
    for (int nt = 0; nt < 4; ++nt) acc[mt][nt] = f32x4{0.f, 0.f, 0.f, 0.f};

  // wave-private DMA of chunk c into private buf bi (4 KB = 4 instrs)
  auto dma = [&](int c, int bi) {
    #pragma unroll
    for (int seg = 0; seg < 2; ++seg) {
      __builtin_amdgcn_global_load_lds(
          (const unsigned int*)(avtg + ((size_t)c << 11) + seg * 1024 + lane * 16),
          (unsigned int*)&AVp[w][bi][seg * 512], 16, 0, 0);
      __builtin_amdgcn_global_load_lds(
          (const unsigned int*)(aktg + ((size_t)c << 11) + seg * 1024 + lane * 16),
          (unsigned int*)&AKp[w][bi][seg * 512], 16, 0, 0);
    }
  };

  auto epilogue = [&](int lt) {
    int l0 = lt * 128;
    int hi = r >> 3;
    int n2 = r & 7;
    #pragma unroll
    for (int mt = 0; mt < 8; ++mt) {
      f16x4 qh[4];
      #pragma unroll
      for (int nt = 0; nt < 4; ++nt)
        qh[nt] = *(const f16x4*)(aqtb + (size_t)(nt * 2 + hi) * L_SEQ
                                 + l0 + mt * 16 + p * 4);
      #pragma unroll
      for (int reg = 0; reg < 4; ++reg) {
        float pv = (float)qh[0][reg] * acc[mt][0][reg]
                 + (float)qh[1][reg] * acc[mt][1][reg]
                 + (float)qh[2][reg] * acc[mt][2][reg]
                 + (float)qh[3][reg] * acc[mt][3][reg];
        pv += __shfl_xor(pv, 8, 64);
        if (r < 8) {
          int i = mt * 16 + p * 4 + reg;
          out[(((size_t)b * NHH + np) * L_SEQ + (l0 + i)) * HDD + hnb + n2] = pv;
        }
      }
    }
  };

  int tA = g * 4 + w;
  int tB = 15 - tA;
  int NCa = tA + 1;                // flat units: [0,NCa) tile A, [NCa,17) tile B

  dma(0, 0);                       // tile A chunk 0
  f16x8 f[14];

  for (int i = 0; i < 17; ++i) {
    int ti = (i >= NCa);
    int lt = ti ? tB : tA;
    int c  = ti ? i - NCa : i;

    if (i == NCa) {                // tile switch: flush A, re-zero
      epilogue(tA);
      #pragma unroll
      for (int mt = 0; mt < 8; ++mt)
        #pragma unroll
        for (int nt = 0; nt < 4; ++nt) acc[mt][nt] = f32x4{0.f, 0.f, 0.f, 0.f};
    }

    // ---- issue af (global, 14 x dwordx4) for this unit
    int dy = 2047 - (lt - c) * 128;
    const f16* fb = aflane + dy;
    #pragma unroll
    for (int dd = 0; dd < 14; ++dd) f[dd] = *(const f16x8*)(fb + 16 * dd);

    // ---- issue next-chunk private DMA, then wait: af done + dma(i) landed,
    //      dma(i+1) (4 newest) stays in flight under this unit's MFMA body
    if (i + 1 < 17) {
      int i2 = i + 1;
      int c2 = (i2 >= NCa) ? i2 - NCa : i2;
      dma(c2, i2 & 1);
      asm volatile("s_waitcnt vmcnt(4)" ::: "memory");
    } else {
      asm volatile("s_waitcnt vmcnt(0)" ::: "memory");
    }
    __builtin_amdgcn_sched_barrier(0);

    // ---- unit: 128 MFMA from private buf (i&1)
    int bi = i & 1;
    int ky = r & 7;
    __builtin_amdgcn_s_setprio(1);
    #pragma unroll
    for (int s = 0; s < 4; ++s) {
      f16x8 kf = *(const f16x8*)&AKp[w][bi][ky * 128 + ((s * 32 + p * 8) ^ (ky * 8))];
      #pragma unroll
      for (int nt = 0; nt < 4; ++nt) {
        int vy = nt * 2 + (r >> 3);
        f16x8 vf = *(const f16x8*)&AVp[w][bi][vy * 128 + ((s * 32 + p * 8) ^ (vy * 8))];
        f16x8 bf = vf * kf;                    // v_pk_mul_f16
        #pragma unroll
        for (int mt = 0; mt < 8; ++mt)
          acc[mt][nt] = __builtin_amdgcn_mfma_f32_16x16x32_f16(
              f[7 + 2 * s - mt], bf, acc[mt][nt], 0, 0, 0);
      }
    }
    __builtin_amdgcn_s_setprio(0);
  }

  epilogue(tB);
}

// ---------------------------------------------------------------------------
extern "C" void kernel_launch(void* const* d_in, const int* in_sizes, int n_in,
                              void* d_out, int out_size, void* d_ws, size_t ws_size,
                              hipStream_t stream) {
  const float* q_in = (const float*)d_in[0];
  const float* k_in = (const float*)d_in[1];
  const float* v_in = (const float*)d_in[2];
  const float* scw  = (const float*)d_in[3];
  const float* scb  = (const float*)d_in[4];
  const float* Dv   = (const float*)d_in[5];
  const float* w0   = (const float*)d_in[6];
  const float* b0   = (const float*)d_in[7];
  const float* w1   = (const float*)d_in[8];
  const float* b1   = (const float*)d_in[9];
  const float* w2   = (const float*)d_in[10];
  const float* b2   = (const float*)d_in[11];
  const float* fr   = (const float*)d_in[12];
  const float* wf   = (const float*)d_in[13];
  const float* md   = (const float*)d_in[14];

  float* ws    = (float*)d_ws;
  float* filt  = ws;                                       // 128*2304 f32 (1.18 MB)
  f16* AqT16   = (f16*)(ws + (size_t)HDD * FSTRIDE);       // 4.19M f16 (8.4 MB)
  f16* Akt16   = AqT16 + (size_t)B_SZ * HDD * NHH * L_SEQ; // 4.19M f16
  f16* Avt16   = Akt16 + (size_t)B_SZ * HDD * 16 * 1024;   // 4.19M f16
  f16* FRSg    = Avt16 + (size_t)B_SZ * HDD * 16 * 1024;   // 128*8*2176 f16 (4.5 MB)

  filter_kernel<<<512, 256, 0, stream>>>(w0, b0, w1, b1, w2, b2, fr, wf, md, Dv, filt);
  frs_prep<<<128, 256, 0, stream>>>(filt, FRSg);
  shortconv_kernel<<<512, 256, 0, stream>>>(q_in, k_in, v_in, scw, scb, AqT16, Akt16, Avt16);
  hyena_main<<<512, 256, 0, stream>>>(AqT16, Akt16, Avt16, FRSg, (float*)d_out);
}